// Round 4
// baseline (492.332 us; speedup 1.0000x reference)
//
#include <hip/hip_runtime.h>

#define D 128
#define H 4

// ---------------------------------------------------------------------------
// Kernel 1: per-node, per-head projections.
//   ps[n][h] = sum_d x[n,d]*w[h,d]*attn[h,d];  pd[n][h] = sum_d x[n,d]*w[h,d]*attn[h,D+d]
// One wave per node; lane covers cols {lane, lane+64}.
// ---------------------------------------------------------------------------
__global__ void proj_kernel(const float* __restrict__ x,
                            const float* __restrict__ w,
                            const float* __restrict__ attn,
                            float* __restrict__ ps,
                            float* __restrict__ pd,
                            int N) {
    int node = (int)(((long long)blockIdx.x * blockDim.x + threadIdx.x) >> 6);
    int lane = threadIdx.x & 63;
    if (node >= N) return;
    float x0 = x[(size_t)node * D + lane];
    float x1 = x[(size_t)node * D + 64 + lane];
#pragma unroll
    for (int h = 0; h < H; ++h) {
        float hv0 = x0 * w[h * D + lane];
        float hv1 = x1 * w[h * D + 64 + lane];
        float psv = hv0 * attn[h * 2 * D + lane]     + hv1 * attn[h * 2 * D + 64 + lane];
        float pdv = hv0 * attn[h * 2 * D + D + lane] + hv1 * attn[h * 2 * D + D + 64 + lane];
#pragma unroll
        for (int off = 32; off > 0; off >>= 1) {
            psv += __shfl_xor(psv, off);
            pdv += __shfl_xor(pdv, off);
        }
        if (lane == 0) {
            ps[(size_t)node * H + h] = psv;
            pd[(size_t)node * H + h] = pdv;
        }
    }
}

// ---------------------------------------------------------------------------
// Kernel 2: histogram of src.
// ---------------------------------------------------------------------------
__global__ void count_kernel(const int* __restrict__ src, int* __restrict__ counts, int E) {
    int e = blockIdx.x * blockDim.x + threadIdx.x;
    if (e < E) atomicAdd(counts + src[e], 1);
}

// ---------------------------------------------------------------------------
// Kernel 3: single-block exclusive scan (shuffle-based), offs[0..N], offs[N]=E.
// 1024 threads = 16 waves; processes 1024 elems/iter with a running carry.
// ---------------------------------------------------------------------------
__global__ void scan_kernel(const int* __restrict__ counts, int* __restrict__ offs, int N) {
    __shared__ int wsum[16];
    __shared__ int woff[17];
    __shared__ int carry_s;
    int tid = threadIdx.x, lane = tid & 63, wid = tid >> 6;
    if (tid == 0) carry_s = 0;
    __syncthreads();
    for (int base = 0; base < N; base += 1024) {
        int i = base + tid;
        int v = (i < N) ? counts[i] : 0;
        int acc = v;
#pragma unroll
        for (int d = 1; d < 64; d <<= 1) {
            int t = __shfl_up(acc, d);
            if (lane >= d) acc += t;
        }
        if (lane == 63) wsum[wid] = acc;
        __syncthreads();                       // A: wsum visible
        int carry = carry_s;                   // all threads snapshot carry
        if (wid == 0) {
            int wv = (lane < 16) ? wsum[lane] : 0;
            int wacc = wv;
#pragma unroll
            for (int d = 1; d < 16; d <<= 1) {
                int t = __shfl_up(wacc, d);
                if (lane >= d) wacc += t;
            }
            if (lane < 16) woff[lane + 1] = wacc;   // inclusive over waves
            if (lane == 0) woff[0] = 0;
        }
        __syncthreads();                       // B: woff visible, carry snapshotted
        if (i < N) offs[i] = carry + woff[wid] + (acc - v);
        __syncthreads();                       // C: woff/wsum reads done
        if (tid == 0) carry_s = carry + woff[16];
        __syncthreads();                       // D: carry update visible
    }
    if (threadIdx.x == 0) offs[N] = carry_s;
}

// ---------------------------------------------------------------------------
// Kernel 4: bucket dst by src into CSR order.
// ---------------------------------------------------------------------------
__global__ void scatter_kernel(const int* __restrict__ src, const int* __restrict__ dst,
                               const int* __restrict__ offs, int* __restrict__ cursor,
                               int* __restrict__ dsts, int E) {
    int e = blockIdx.x * blockDim.x + threadIdx.x;
    if (e >= E) return;
    int s = src[e];
    int pos = offs[s] + atomicAdd(cursor + s, 1);
    dsts[pos] = dst[e];
}

// ---------------------------------------------------------------------------
// Kernel 5: per-node gather + fused normalize.
// One wave per node; lane covers cols {lane, lane+64}. All 4 heads in regs.
//   out[h][n][d] = (sum_j e_hj * x[j,d]) * w[h,d] / (sum_j e_hj)
// ---------------------------------------------------------------------------
__global__ void gather_kernel(const float* __restrict__ x,
                              const float* __restrict__ w,
                              const float* __restrict__ ps,
                              const float* __restrict__ pd,
                              const int* __restrict__ offs,
                              const int* __restrict__ dsts,
                              float* __restrict__ out,
                              int N) {
    int node = (int)(((long long)blockIdx.x * blockDim.x + threadIdx.x) >> 6);
    int lane = threadIdx.x & 63;
    if (node >= N) return;
    const float4 ps4 = *(const float4*)(ps + (size_t)node * H);
    float a00 = 0, a01 = 0, a10 = 0, a11 = 0, a20 = 0, a21 = 0, a30 = 0, a31 = 0;
    float rs0 = 0, rs1 = 0, rs2 = 0, rs3 = 0;
    int beg = offs[node], end = offs[node + 1];
    int t = (beg < end) ? dsts[beg] : 0;
    for (int k = beg; k < end; ++k) {
        int tn = (k + 1 < end) ? dsts[k + 1] : 0;   // prefetch next index
        const float4 pd4 = *(const float4*)(pd + (size_t)t * H);
        float x0 = x[(size_t)t * D + lane];
        float x1 = x[(size_t)t * D + 64 + lane];
        float s0 = ps4.x + pd4.x; s0 = s0 > 0.f ? s0 : 0.2f * s0; float e0 = __expf(-s0);
        float s1 = ps4.y + pd4.y; s1 = s1 > 0.f ? s1 : 0.2f * s1; float e1 = __expf(-s1);
        float s2 = ps4.z + pd4.z; s2 = s2 > 0.f ? s2 : 0.2f * s2; float e2 = __expf(-s2);
        float s3 = ps4.w + pd4.w; s3 = s3 > 0.f ? s3 : 0.2f * s3; float e3 = __expf(-s3);
        a00 += e0 * x0; a01 += e0 * x1; rs0 += e0;
        a10 += e1 * x0; a11 += e1 * x1; rs1 += e1;
        a20 += e2 * x0; a21 += e2 * x1; rs2 += e2;
        a30 += e3 * x0; a31 += e3 * x1; rs3 += e3;
        t = tn;
    }
    size_t nd = (size_t)N * D;
    size_t b = (size_t)node * D + lane;
    out[0 * nd + b]      = a00 * w[0 * D + lane]      / rs0;
    out[0 * nd + b + 64] = a01 * w[0 * D + 64 + lane] / rs0;
    out[1 * nd + b]      = a10 * w[1 * D + lane]      / rs1;
    out[1 * nd + b + 64] = a11 * w[1 * D + 64 + lane] / rs1;
    out[2 * nd + b]      = a20 * w[2 * D + lane]      / rs2;
    out[2 * nd + b + 64] = a21 * w[2 * D + 64 + lane] / rs2;
    out[3 * nd + b]      = a30 * w[3 * D + lane]      / rs3;
    out[3 * nd + b + 64] = a31 * w[3 * D + 64 + lane] / rs3;
}

extern "C" void kernel_launch(void* const* d_in, const int* in_sizes, int n_in,
                              void* d_out, int out_size, void* d_ws, size_t ws_size,
                              hipStream_t stream) {
    const float* x    = (const float*)d_in[0];
    const float* w    = (const float*)d_in[1];
    const float* attn = (const float*)d_in[2];
    const int*   edge = (const int*)d_in[3];

    int N = in_sizes[0] / D;
    int E = in_sizes[3] / 2;
    const int* src = edge;
    const int* dst = edge + E;

    float* out = (float*)d_out;

    // workspace layout (all 16B-aligned: N*H*4 = 1.6MB blocks)
    char* wsp = (char*)d_ws;
    float* ps     = (float*)wsp;                         wsp += (size_t)N * H * sizeof(float);
    float* pd     = (float*)wsp;                         wsp += (size_t)N * H * sizeof(float);
    int*   counts = (int*)wsp;                           wsp += (size_t)N * sizeof(int);
    int*   cursor = (int*)wsp;                           wsp += (size_t)N * sizeof(int);
    int*   offs   = (int*)wsp;                           wsp += (size_t)(N + 1) * sizeof(int);
    int*   dsts   = (int*)wsp;

    hipMemsetAsync(counts, 0, (size_t)N * sizeof(int), stream);
    hipMemsetAsync(cursor, 0, (size_t)N * sizeof(int), stream);

    proj_kernel<<<(N + 3) / 4, 256, 0, stream>>>(x, w, attn, ps, pd, N);
    count_kernel<<<(E + 255) / 256, 256, 0, stream>>>(src, counts, E);
    scan_kernel<<<1, 1024, 0, stream>>>(counts, offs, N);
    scatter_kernel<<<(E + 255) / 256, 256, 0, stream>>>(src, dst, offs, cursor, dsts, E);
    gather_kernel<<<(N + 3) / 4, 256, 0, stream>>>(x, w, ps, pd, offs, dsts, out, N);
}

// Round 5
// 427.008 us; speedup vs baseline: 1.1530x; 1.1530x over previous
//
#include <hip/hip_runtime.h>

#define D 128
#define H 4

// ---------------------------------------------------------------------------
// Kernel 1: per-node, per-head projections.
//   ps[n][h] = sum_d x[n,d]*w[h,d]*attn[h,d];  pd[n][h] = sum_d x[n,d]*w[h,d]*attn[h,D+d]
// One wave per node; lane covers cols {lane, lane+64}.
// ---------------------------------------------------------------------------
__global__ void proj_kernel(const float* __restrict__ x,
                            const float* __restrict__ w,
                            const float* __restrict__ attn,
                            float* __restrict__ ps,
                            float* __restrict__ pd,
                            int N) {
    int node = (int)(((long long)blockIdx.x * blockDim.x + threadIdx.x) >> 6);
    int lane = threadIdx.x & 63;
    if (node >= N) return;
    float x0 = x[(size_t)node * D + lane];
    float x1 = x[(size_t)node * D + 64 + lane];
#pragma unroll
    for (int h = 0; h < H; ++h) {
        float hv0 = x0 * w[h * D + lane];
        float hv1 = x1 * w[h * D + 64 + lane];
        float psv = hv0 * attn[h * 2 * D + lane]     + hv1 * attn[h * 2 * D + 64 + lane];
        float pdv = hv0 * attn[h * 2 * D + D + lane] + hv1 * attn[h * 2 * D + D + 64 + lane];
#pragma unroll
        for (int off = 32; off > 0; off >>= 1) {
            psv += __shfl_xor(psv, off);
            pdv += __shfl_xor(pdv, off);
        }
        if (lane == 0) {
            ps[(size_t)node * H + h] = psv;
            pd[(size_t)node * H + h] = pdv;
        }
    }
}

// ---------------------------------------------------------------------------
// Kernel 2: histogram of src.
// ---------------------------------------------------------------------------
__global__ void count_kernel(const int* __restrict__ src, int* __restrict__ counts, int E) {
    int e = blockIdx.x * blockDim.x + threadIdx.x;
    if (e < E) atomicAdd(counts + src[e], 1);
}

// ---------------------------------------------------------------------------
// Hierarchical scan, pass 1: each 1024-thread block scans 1024 counts
// (block-local exclusive into offs) and writes its block total to bsum.
// ---------------------------------------------------------------------------
__global__ void scan1_kernel(const int* __restrict__ counts,
                             int* __restrict__ offs,
                             int* __restrict__ bsum, int N) {
    __shared__ int wsum[16];
    __shared__ int woffi[16];
    int tid = threadIdx.x, lane = tid & 63, wid = tid >> 6;
    int i = blockIdx.x * 1024 + tid;
    int v = (i < N) ? counts[i] : 0;
    int acc = v;
#pragma unroll
    for (int d = 1; d < 64; d <<= 1) {
        int t = __shfl_up(acc, d);
        if (lane >= d) acc += t;
    }
    if (lane == 63) wsum[wid] = acc;
    __syncthreads();
    if (wid == 0) {
        int wv = (lane < 16) ? wsum[lane] : 0;
        int wacc = wv;
#pragma unroll
        for (int d = 1; d < 16; d <<= 1) {
            int t = __shfl_up(wacc, d);
            if (lane >= d) wacc += t;
        }
        if (lane < 16) woffi[lane] = wacc;   // inclusive over waves
    }
    __syncthreads();
    int bexcl = (wid == 0) ? 0 : woffi[wid - 1];
    if (i < N) offs[i] = bexcl + (acc - v);
    if (tid == 0) bsum[blockIdx.x] = woffi[15];
}

// ---------------------------------------------------------------------------
// Pass 2: one wave scans the block sums (exclusive, in-place safe via regs).
// Lane handles k consecutive elements; supports nb <= 64*8.
// ---------------------------------------------------------------------------
__global__ void scan2_kernel(const int* __restrict__ bsum, int* __restrict__ boff, int nb) {
    int lane = threadIdx.x;
    int k = (nb + 63) >> 6;
    int local[8];
    int s = 0;
#pragma unroll 8
    for (int j = 0; j < k; ++j) {
        int idx = lane * k + j;
        local[j] = (idx < nb) ? bsum[idx] : 0;
        s += local[j];
    }
    int acc = s;
#pragma unroll
    for (int d = 1; d < 64; d <<= 1) {
        int t = __shfl_up(acc, d);
        if (lane >= d) acc += t;
    }
    int excl = acc - s;
#pragma unroll 8
    for (int j = 0; j < k; ++j) {
        int idx = lane * k + j;
        if (idx < nb) boff[idx] = excl;
        excl += local[j];
    }
}

// ---------------------------------------------------------------------------
// Pass 3: add block offsets; also init cursor = offs and offs[N] = E.
// ---------------------------------------------------------------------------
__global__ void scan3_kernel(int* __restrict__ offs, int* __restrict__ cursor,
                             const int* __restrict__ boff, int N, int E) {
    int i = blockIdx.x * blockDim.x + threadIdx.x;
    if (i < N) {
        int o = offs[i] + boff[i >> 10];
        offs[i] = o;
        cursor[i] = o;
    }
    if (i == 0) offs[N] = E;
}

// ---------------------------------------------------------------------------
// Kernel 4: bucket dst by src into CSR order; optionally compute the 4 head
// edge-weights once per edge and store float4 e_csr[pos].
// ---------------------------------------------------------------------------
template <bool WITH_E>
__global__ void scatter_kernel(const int* __restrict__ src, const int* __restrict__ dst,
                               int* __restrict__ cursor, int* __restrict__ dsts,
                               const float* __restrict__ ps, const float* __restrict__ pd,
                               float4* __restrict__ e_csr, int E) {
    int e = blockIdx.x * blockDim.x + threadIdx.x;
    if (e >= E) return;
    int s = src[e];
    int t = dst[e];
    int pos = atomicAdd(cursor + s, 1);
    dsts[pos] = t;
    if (WITH_E) {
        const float4 ps4 = *(const float4*)(ps + (size_t)s * H);
        const float4 pd4 = *(const float4*)(pd + (size_t)t * H);
        float s0 = ps4.x + pd4.x; s0 = s0 > 0.f ? s0 : 0.2f * s0;
        float s1 = ps4.y + pd4.y; s1 = s1 > 0.f ? s1 : 0.2f * s1;
        float s2 = ps4.z + pd4.z; s2 = s2 > 0.f ? s2 : 0.2f * s2;
        float s3 = ps4.w + pd4.w; s3 = s3 > 0.f ? s3 : 0.2f * s3;
        e_csr[pos] = make_float4(__expf(-s0), __expf(-s1), __expf(-s2), __expf(-s3));
    }
}

// ---------------------------------------------------------------------------
// Kernel 5: per-node gather + fused normalize.
// One wave per node; lane covers cols {2*lane, 2*lane+1} (float2).
//   out[h][n][d] = (sum_j e_hj * x[j,d]) * w[h,d] / (sum_j e_hj)
// ---------------------------------------------------------------------------
template <bool WITH_E>
__global__ void gather_kernel(const float* __restrict__ x,
                              const float* __restrict__ w,
                              const float* __restrict__ ps,
                              const float* __restrict__ pd,
                              const int* __restrict__ offs,
                              const int* __restrict__ dsts,
                              const float4* __restrict__ e_csr,
                              float* __restrict__ out,
                              int N) {
    int node = (int)(((long long)blockIdx.x * blockDim.x + threadIdx.x) >> 6);
    int lane = threadIdx.x & 63;
    if (node >= N) return;
    float4 ps4 = make_float4(0.f, 0.f, 0.f, 0.f);
    if (!WITH_E) ps4 = *(const float4*)(ps + (size_t)node * H);
    float a0x = 0, a0y = 0, a1x = 0, a1y = 0, a2x = 0, a2y = 0, a3x = 0, a3y = 0;
    float rs0 = 0, rs1 = 0, rs2 = 0, rs3 = 0;
    int beg = offs[node], end = offs[node + 1];
    for (int k = beg; k < end; ++k) {
        int t = dsts[k];
        float4 e4;
        if (WITH_E) {
            e4 = e_csr[k];
        } else {
            const float4 pd4 = *(const float4*)(pd + (size_t)t * H);
            float s0 = ps4.x + pd4.x; s0 = s0 > 0.f ? s0 : 0.2f * s0;
            float s1 = ps4.y + pd4.y; s1 = s1 > 0.f ? s1 : 0.2f * s1;
            float s2 = ps4.z + pd4.z; s2 = s2 > 0.f ? s2 : 0.2f * s2;
            float s3 = ps4.w + pd4.w; s3 = s3 > 0.f ? s3 : 0.2f * s3;
            e4 = make_float4(__expf(-s0), __expf(-s1), __expf(-s2), __expf(-s3));
        }
        const float2 xv = *(const float2*)(x + (size_t)t * D + lane * 2);
        a0x += e4.x * xv.x; a0y += e4.x * xv.y; rs0 += e4.x;
        a1x += e4.y * xv.x; a1y += e4.y * xv.y; rs1 += e4.y;
        a2x += e4.z * xv.x; a2y += e4.z * xv.y; rs2 += e4.z;
        a3x += e4.w * xv.x; a3y += e4.w * xv.y; rs3 += e4.w;
    }
    float i0 = 1.0f / rs0, i1 = 1.0f / rs1, i2 = 1.0f / rs2, i3 = 1.0f / rs3;
    size_t nd = (size_t)N * D;
    size_t b = (size_t)node * D + lane * 2;
    const float2 w0 = *(const float2*)(w + 0 * D + lane * 2);
    const float2 w1 = *(const float2*)(w + 1 * D + lane * 2);
    const float2 w2 = *(const float2*)(w + 2 * D + lane * 2);
    const float2 w3 = *(const float2*)(w + 3 * D + lane * 2);
    *(float2*)(out + 0 * nd + b) = make_float2(a0x * w0.x * i0, a0y * w0.y * i0);
    *(float2*)(out + 1 * nd + b) = make_float2(a1x * w1.x * i1, a1y * w1.y * i1);
    *(float2*)(out + 2 * nd + b) = make_float2(a2x * w2.x * i2, a2y * w2.y * i2);
    *(float2*)(out + 3 * nd + b) = make_float2(a3x * w3.x * i3, a3y * w3.y * i3);
}

extern "C" void kernel_launch(void* const* d_in, const int* in_sizes, int n_in,
                              void* d_out, int out_size, void* d_ws, size_t ws_size,
                              hipStream_t stream) {
    const float* x    = (const float*)d_in[0];
    const float* w    = (const float*)d_in[1];
    const float* attn = (const float*)d_in[2];
    const int*   edge = (const int*)d_in[3];

    int N = in_sizes[0] / D;
    int E = in_sizes[3] / 2;
    const int* src = edge;
    const int* dst = edge + E;
    float* out = (float*)d_out;

    int nb = (N + 1023) / 1024;   // scan blocks (<= 512 supported by scan2)

    // workspace layout — e_csr first for 16B alignment
    char* wsp = (char*)d_ws;
    float4* e_csr = (float4*)wsp;
    size_t e_bytes = (size_t)E * sizeof(float4);
    size_t rest =
        2 * (size_t)N * H * sizeof(float)   // ps, pd
        + 2 * (size_t)N * sizeof(int)       // counts, cursor
        + ((size_t)N + 1) * sizeof(int)     // offs
        + 2 * (size_t)nb * sizeof(int)      // bsum, boff
        + (size_t)E * sizeof(int);          // dsts
    bool with_e = ws_size >= e_bytes + rest + 1024;
    if (with_e) wsp += e_bytes;

    float* ps     = (float*)wsp;   wsp += (size_t)N * H * sizeof(float);
    float* pd     = (float*)wsp;   wsp += (size_t)N * H * sizeof(float);
    int*   counts = (int*)wsp;     wsp += (size_t)N * sizeof(int);
    int*   cursor = (int*)wsp;     wsp += (size_t)N * sizeof(int);
    int*   offs   = (int*)wsp;     wsp += ((size_t)N + 1) * sizeof(int);
    int*   bsum   = (int*)wsp;     wsp += (size_t)nb * sizeof(int);
    int*   boff   = (int*)wsp;     wsp += (size_t)nb * sizeof(int);
    int*   dsts   = (int*)wsp;

    hipMemsetAsync(counts, 0, (size_t)N * sizeof(int), stream);

    proj_kernel<<<(N + 3) / 4, 256, 0, stream>>>(x, w, attn, ps, pd, N);
    count_kernel<<<(E + 255) / 256, 256, 0, stream>>>(src, counts, E);
    scan1_kernel<<<nb, 1024, 0, stream>>>(counts, offs, bsum, N);
    scan2_kernel<<<1, 64, 0, stream>>>(bsum, boff, nb);
    scan3_kernel<<<(N + 255) / 256, 256, 0, stream>>>(offs, cursor, boff, N, E);
    if (with_e) {
        scatter_kernel<true><<<(E + 255) / 256, 256, 0, stream>>>(src, dst, cursor, dsts, ps, pd, e_csr, E);
        gather_kernel<true><<<(N + 3) / 4, 256, 0, stream>>>(x, w, ps, pd, offs, dsts, e_csr, out, N);
    } else {
        scatter_kernel<false><<<(E + 255) / 256, 256, 0, stream>>>(src, dst, cursor, dsts, ps, pd, e_csr, E);
        gather_kernel<false><<<(N + 3) / 4, 256, 0, stream>>>(x, w, ps, pd, offs, dsts, e_csr, out, N);
    }
}

// Round 8
// 392.200 us; speedup vs baseline: 1.2553x; 1.0888x over previous
//
#include <hip/hip_runtime.h>
#include <hip/hip_fp16.h>

#define D 128
#define H 4

// ---------------------------------------------------------------------------
// Kernel 1: per-node, per-head projections.
//   ps[n][h] = sum_d x[n,d]*w[h,d]*attn[h,d];  pd[n][h] = sum_d x[n,d]*w[h,d]*attn[h,D+d]
// ---------------------------------------------------------------------------
__global__ void proj_kernel(const float* __restrict__ x,
                            const float* __restrict__ w,
                            const float* __restrict__ attn,
                            float* __restrict__ ps,
                            float* __restrict__ pd,
                            int N) {
    int node = (int)(((long long)blockIdx.x * blockDim.x + threadIdx.x) >> 6);
    int lane = threadIdx.x & 63;
    if (node >= N) return;
    float x0 = x[(size_t)node * D + lane];
    float x1 = x[(size_t)node * D + 64 + lane];
#pragma unroll
    for (int h = 0; h < H; ++h) {
        float hv0 = x0 * w[h * D + lane];
        float hv1 = x1 * w[h * D + 64 + lane];
        float psv = hv0 * attn[h * 2 * D + lane]     + hv1 * attn[h * 2 * D + 64 + lane];
        float pdv = hv0 * attn[h * 2 * D + D + lane] + hv1 * attn[h * 2 * D + D + 64 + lane];
#pragma unroll
        for (int off = 32; off > 0; off >>= 1) {
            psv += __shfl_xor(psv, off);
            pdv += __shfl_xor(pdv, off);
        }
        if (lane == 0) {
            ps[(size_t)node * H + h] = psv;
            pd[(size_t)node * H + h] = pdv;
        }
    }
}

// ---------------------------------------------------------------------------
// Kernel 2: histogram of src.
// ---------------------------------------------------------------------------
__global__ void count_kernel(const int* __restrict__ src, int* __restrict__ counts, int E) {
    int e = blockIdx.x * blockDim.x + threadIdx.x;
    if (e < E) atomicAdd(counts + src[e], 1);
}

// ---------------------------------------------------------------------------
// Scan pass 1: block-local exclusive scan of counts; block total to bsum.
// ---------------------------------------------------------------------------
__global__ void scan1_kernel(const int* __restrict__ counts,
                             int* __restrict__ offs,
                             int* __restrict__ bsum, int N) {
    __shared__ int wsum[16];
    __shared__ int woffi[16];
    int tid = threadIdx.x, lane = tid & 63, wid = tid >> 6;
    int i = blockIdx.x * 1024 + tid;
    int v = (i < N) ? counts[i] : 0;
    int acc = v;
#pragma unroll
    for (int d = 1; d < 64; d <<= 1) {
        int t = __shfl_up(acc, d);
        if (lane >= d) acc += t;
    }
    if (lane == 63) wsum[wid] = acc;
    __syncthreads();
    if (wid == 0) {
        int wv = (lane < 16) ? wsum[lane] : 0;
        int wacc = wv;
#pragma unroll
        for (int d = 1; d < 16; d <<= 1) {
            int t = __shfl_up(wacc, d);
            if (lane >= d) wacc += t;
        }
        if (lane < 16) woffi[lane] = wacc;
    }
    __syncthreads();
    int bexcl = (wid == 0) ? 0 : woffi[wid - 1];
    if (i < N) offs[i] = bexcl + (acc - v);
    if (tid == 0) bsum[blockIdx.x] = woffi[15];
}

// ---------------------------------------------------------------------------
// Scan pass 2: one wave scans block sums (supports nb <= 512).
// ---------------------------------------------------------------------------
__global__ void scan2_kernel(const int* __restrict__ bsum, int* __restrict__ boff, int nb) {
    int lane = threadIdx.x;
    int k = (nb + 63) >> 6;
    int local[8];
    int s = 0;
#pragma unroll 8
    for (int j = 0; j < k; ++j) {
        int idx = lane * k + j;
        local[j] = (idx < nb) ? bsum[idx] : 0;
        s += local[j];
    }
    int acc = s;
#pragma unroll
    for (int d = 1; d < 64; d <<= 1) {
        int t = __shfl_up(acc, d);
        if (lane >= d) acc += t;
    }
    int excl = acc - s;
#pragma unroll 8
    for (int j = 0; j < k; ++j) {
        int idx = lane * k + j;
        if (idx < nb) boff[idx] = excl;
        excl += local[j];
    }
}

// ---------------------------------------------------------------------------
// Scan pass 3: add block offsets; init cursor = offs; offs[N] = E.
// ---------------------------------------------------------------------------
__global__ void scan3_kernel(int* __restrict__ offs, int* __restrict__ cursor,
                             const int* __restrict__ boff, int N, int E) {
    int i = blockIdx.x * blockDim.x + threadIdx.x;
    if (i < N) {
        int o = offs[i] + boff[i >> 10];
        offs[i] = o;
        cursor[i] = o;
    }
    if (i == 0) offs[N] = E;
}

// ---------------------------------------------------------------------------
// Kernel 4: bucket dst by src into CSR order; compute the 4 head edge-weights
// once per edge, packed as 4 x fp16 (8 B).
// ---------------------------------------------------------------------------
__global__ void scatter_kernel(const int* __restrict__ src, const int* __restrict__ dst,
                               int* __restrict__ cursor, int* __restrict__ dsts,
                               const float* __restrict__ ps, const float* __restrict__ pd,
                               uint2* __restrict__ e_csr, int E) {
    int e = blockIdx.x * blockDim.x + threadIdx.x;
    if (e >= E) return;
    int s = src[e];
    int t = dst[e];
    int pos = atomicAdd(cursor + s, 1);
    dsts[pos] = t;
    const float4 ps4 = *(const float4*)(ps + (size_t)s * H);
    const float4 pd4 = *(const float4*)(pd + (size_t)t * H);
    float s0 = ps4.x + pd4.x; s0 = s0 > 0.f ? s0 : 0.2f * s0;
    float s1 = ps4.y + pd4.y; s1 = s1 > 0.f ? s1 : 0.2f * s1;
    float s2 = ps4.z + pd4.z; s2 = s2 > 0.f ? s2 : 0.2f * s2;
    float s3 = ps4.w + pd4.w; s3 = s3 > 0.f ? s3 : 0.2f * s3;
    union { __half2 h[2]; uint2 u; } pk;
    pk.h[0] = __floats2half2_rn(__expf(-s0), __expf(-s1));
    pk.h[1] = __floats2half2_rn(__expf(-s2), __expf(-s3));
    e_csr[pos] = pk.u;
}

// ---------------------------------------------------------------------------
// Kernel 5: per-node gather + fused normalize, 8-deep pipelined (MLP=8).
// One wave per node; lane covers cols {2*lane, 2*lane+1}.
// NOTE: macro index j is a REGISTER SLOT; it also offsets k by j, so these
// macros are only valid in the body of the 8-wide loop. The tail loop is
// hand-written (round-7 bug: GLOAD(9) in the tail read dsts[k+9] -> OOB).
// ---------------------------------------------------------------------------
union EPack { __half2 h[2]; uint2 u; };

#define GDECL(j) int t##j; uint2 eu##j; float2 v##j;
#define GLOAD(j) t##j = dsts[k + j]; eu##j = e_csr[k + j];
#define GXLOAD(j) v##j = *(const float2*)(x + (size_t)t##j * D + lane2);
#define GACC(j) { EPack pk; pk.u = eu##j;                                   \
    float e0 = __low2float(pk.h[0]),  e1 = __high2float(pk.h[0]);           \
    float e2 = __low2float(pk.h[1]),  e3 = __high2float(pk.h[1]);           \
    a0x += e0 * v##j.x; a0y += e0 * v##j.y; rs0 += e0;                      \
    a1x += e1 * v##j.x; a1y += e1 * v##j.y; rs1 += e1;                      \
    a2x += e2 * v##j.x; a2y += e2 * v##j.y; rs2 += e2;                      \
    a3x += e3 * v##j.x; a3y += e3 * v##j.y; rs3 += e3; }

__global__ void gather_kernel(const float* __restrict__ x,
                              const float* __restrict__ w,
                              const int* __restrict__ offs,
                              const int* __restrict__ dsts,
                              const uint2* __restrict__ e_csr,
                              float* __restrict__ out,
                              int N) {
    int node = (int)(((long long)blockIdx.x * blockDim.x + threadIdx.x) >> 6);
    int lane = threadIdx.x & 63;
    if (node >= N) return;
    int lane2 = lane * 2;
    float a0x = 0, a0y = 0, a1x = 0, a1y = 0, a2x = 0, a2y = 0, a3x = 0, a3y = 0;
    float rs0 = 0, rs1 = 0, rs2 = 0, rs3 = 0;
    int beg = offs[node], end = offs[node + 1];
    int k = beg;
    for (; k + 8 <= end; k += 8) {
        GDECL(0) GDECL(1) GDECL(2) GDECL(3) GDECL(4) GDECL(5) GDECL(6) GDECL(7)
        GLOAD(0) GLOAD(1) GLOAD(2) GLOAD(3) GLOAD(4) GLOAD(5) GLOAD(6) GLOAD(7)
        GXLOAD(0) GXLOAD(1) GXLOAD(2) GXLOAD(3) GXLOAD(4) GXLOAD(5) GXLOAD(6) GXLOAD(7)
        GACC(0) GACC(1) GACC(2) GACC(3) GACC(4) GACC(5) GACC(6) GACC(7)
    }
    for (; k < end; ++k) {                 // hand-written tail: index k ONLY
        int t = dsts[k];
        EPack pk; pk.u = e_csr[k];
        float2 v = *(const float2*)(x + (size_t)t * D + lane2);
        float e0 = __low2float(pk.h[0]),  e1 = __high2float(pk.h[0]);
        float e2 = __low2float(pk.h[1]),  e3 = __high2float(pk.h[1]);
        a0x += e0 * v.x; a0y += e0 * v.y; rs0 += e0;
        a1x += e1 * v.x; a1y += e1 * v.y; rs1 += e1;
        a2x += e2 * v.x; a2y += e2 * v.y; rs2 += e2;
        a3x += e3 * v.x; a3y += e3 * v.y; rs3 += e3;
    }
    float i0 = 1.0f / rs0, i1 = 1.0f / rs1, i2 = 1.0f / rs2, i3 = 1.0f / rs3;
    size_t nd = (size_t)N * D;
    size_t b = (size_t)node * D + lane2;
    const float2 w0 = *(const float2*)(w + 0 * D + lane2);
    const float2 w1 = *(const float2*)(w + 1 * D + lane2);
    const float2 w2 = *(const float2*)(w + 2 * D + lane2);
    const float2 w3 = *(const float2*)(w + 3 * D + lane2);
    *(float2*)(out + 0 * nd + b) = make_float2(a0x * w0.x * i0, a0y * w0.y * i0);
    *(float2*)(out + 1 * nd + b) = make_float2(a1x * w1.x * i1, a1y * w1.y * i1);
    *(float2*)(out + 2 * nd + b) = make_float2(a2x * w2.x * i2, a2y * w2.y * i2);
    *(float2*)(out + 3 * nd + b) = make_float2(a3x * w3.x * i3, a3y * w3.y * i3);
}

extern "C" void kernel_launch(void* const* d_in, const int* in_sizes, int n_in,
                              void* d_out, int out_size, void* d_ws, size_t ws_size,
                              hipStream_t stream) {
    const float* x    = (const float*)d_in[0];
    const float* w    = (const float*)d_in[1];
    const float* attn = (const float*)d_in[2];
    const int*   edge = (const int*)d_in[3];

    int N = in_sizes[0] / D;
    int E = in_sizes[3] / 2;
    const int* src = edge;
    const int* dst = edge + E;
    float* out = (float*)d_out;

    int nb = (N + 1023) / 1024;

    // workspace layout (e_csr first for 16B alignment)
    char* wsp = (char*)d_ws;
    uint2* e_csr = (uint2*)wsp;    wsp += (size_t)E * sizeof(uint2);
    float* ps     = (float*)wsp;   wsp += (size_t)N * H * sizeof(float);
    float* pd     = (float*)wsp;   wsp += (size_t)N * H * sizeof(float);
    int*   counts = (int*)wsp;     wsp += (size_t)N * sizeof(int);
    int*   cursor = (int*)wsp;     wsp += (size_t)N * sizeof(int);
    int*   offs   = (int*)wsp;     wsp += ((size_t)N + 1) * sizeof(int);
    int*   bsum   = (int*)wsp;     wsp += (size_t)nb * sizeof(int);
    int*   boff   = (int*)wsp;     wsp += (size_t)nb * sizeof(int);
    int*   dsts   = (int*)wsp;

    hipMemsetAsync(counts, 0, (size_t)N * sizeof(int), stream);

    proj_kernel<<<(N + 3) / 4, 256, 0, stream>>>(x, w, attn, ps, pd, N);
    count_kernel<<<(E + 255) / 256, 256, 0, stream>>>(src, counts, E);
    scan1_kernel<<<nb, 1024, 0, stream>>>(counts, offs, bsum, N);
    scan2_kernel<<<1, 64, 0, stream>>>(bsum, boff, nb);
    scan3_kernel<<<(N + 255) / 256, 256, 0, stream>>>(offs, cursor, boff, N, E);
    scatter_kernel<<<(E + 255) / 256, 256, 0, stream>>>(src, dst, cursor, dsts, ps, pd, e_csr, E);
    gather_kernel<<<(N + 3) / 4, 256, 0, stream>>>(x, w, offs, dsts, e_csr, out, N);
}

// Round 9
// 354.254 us; speedup vs baseline: 1.3898x; 1.1071x over previous
//
#include <hip/hip_runtime.h>
#include <hip/hip_fp16.h>

#define D 128
#define H 4

typedef float fvec2 __attribute__((ext_vector_type(2)));
typedef unsigned int uvec4 __attribute__((ext_vector_type(4)));

// ---------------------------------------------------------------------------
// Kernel 1 (fused): blocks [0,nbP) compute per-node projections ps/pd;
// blocks [nbP, nbP+nbC) histogram src AND record each edge's rank
// (rank[e] = old count) so the CSR scatter needs no second atomic.
// ---------------------------------------------------------------------------
__global__ void proj_count_kernel(const float* __restrict__ x,
                                  const float* __restrict__ w,
                                  const float* __restrict__ attn,
                                  float* __restrict__ ps,
                                  float* __restrict__ pd,
                                  const int* __restrict__ src,
                                  int* __restrict__ counts,
                                  int* __restrict__ rank,
                                  int N, int E, int nbP) {
    int bid = blockIdx.x;
    if (bid < nbP) {
        int node = (int)(((long long)bid * blockDim.x + threadIdx.x) >> 6);
        int lane = threadIdx.x & 63;
        if (node >= N) return;
        float x0 = x[(size_t)node * D + lane];
        float x1 = x[(size_t)node * D + 64 + lane];
#pragma unroll
        for (int h = 0; h < H; ++h) {
            float hv0 = x0 * w[h * D + lane];
            float hv1 = x1 * w[h * D + 64 + lane];
            float psv = hv0 * attn[h * 2 * D + lane]     + hv1 * attn[h * 2 * D + 64 + lane];
            float pdv = hv0 * attn[h * 2 * D + D + lane] + hv1 * attn[h * 2 * D + D + 64 + lane];
#pragma unroll
            for (int off = 32; off > 0; off >>= 1) {
                psv += __shfl_xor(psv, off);
                pdv += __shfl_xor(pdv, off);
            }
            if (lane == 0) {
                ps[(size_t)node * H + h] = psv;
                pd[(size_t)node * H + h] = pdv;
            }
        }
    } else {
        int e = (bid - nbP) * blockDim.x + threadIdx.x;
        if (e < E) rank[e] = atomicAdd(counts + src[e], 1);
    }
}

// ---------------------------------------------------------------------------
// Scan pass 1: block-local exclusive scan of counts; block total to bsum.
// ---------------------------------------------------------------------------
__global__ void scan1_kernel(const int* __restrict__ counts,
                             int* __restrict__ offs,
                             int* __restrict__ bsum, int N) {
    __shared__ int wsum[16];
    __shared__ int woffi[16];
    int tid = threadIdx.x, lane = tid & 63, wid = tid >> 6;
    int i = blockIdx.x * 1024 + tid;
    int v = (i < N) ? counts[i] : 0;
    int acc = v;
#pragma unroll
    for (int d = 1; d < 64; d <<= 1) {
        int t = __shfl_up(acc, d);
        if (lane >= d) acc += t;
    }
    if (lane == 63) wsum[wid] = acc;
    __syncthreads();
    if (wid == 0) {
        int wv = (lane < 16) ? wsum[lane] : 0;
        int wacc = wv;
#pragma unroll
        for (int d = 1; d < 16; d <<= 1) {
            int t = __shfl_up(wacc, d);
            if (lane >= d) wacc += t;
        }
        if (lane < 16) woffi[lane] = wacc;
    }
    __syncthreads();
    int bexcl = (wid == 0) ? 0 : woffi[wid - 1];
    if (i < N) offs[i] = bexcl + (acc - v);
    if (tid == 0) bsum[blockIdx.x] = woffi[15];
}

// ---------------------------------------------------------------------------
// Scan pass 2: one wave scans block sums (supports nb <= 512).
// ---------------------------------------------------------------------------
__global__ void scan2_kernel(const int* __restrict__ bsum, int* __restrict__ boff, int nb) {
    int lane = threadIdx.x;
    int k = (nb + 63) >> 6;
    int local[8];
    int s = 0;
#pragma unroll 8
    for (int j = 0; j < k; ++j) {
        int idx = lane * k + j;
        local[j] = (idx < nb) ? bsum[idx] : 0;
        s += local[j];
    }
    int acc = s;
#pragma unroll
    for (int d = 1; d < 64; d <<= 1) {
        int t = __shfl_up(acc, d);
        if (lane >= d) acc += t;
    }
    int excl = acc - s;
#pragma unroll 8
    for (int j = 0; j < k; ++j) {
        int idx = lane * k + j;
        if (idx < nb) boff[idx] = excl;
        excl += local[j];
    }
}

// ---------------------------------------------------------------------------
// Scan pass 3: add block offsets; offs[N] = E.
// ---------------------------------------------------------------------------
__global__ void scan3_kernel(int* __restrict__ offs, const int* __restrict__ boff,
                             int N, int E) {
    int i = blockIdx.x * blockDim.x + threadIdx.x;
    if (i < N) offs[i] += boff[i >> 10];
    if (i == 0) offs[N] = E;
}

// ---------------------------------------------------------------------------
// Kernel 4: CSR scatter, atomic-free (pos = offs[src] + rank[e]).
// Packs {dst, e01_fp16, e23_fp16} into ONE 16-byte record -> one random
// cache-line RMW per edge.
// ---------------------------------------------------------------------------
__global__ void scatter_kernel(const int* __restrict__ src, const int* __restrict__ dst,
                               const int* __restrict__ rank, const int* __restrict__ offs,
                               const float* __restrict__ ps, const float* __restrict__ pd,
                               uint4* __restrict__ ec, int E) {
    int e = blockIdx.x * blockDim.x + threadIdx.x;
    if (e >= E) return;
    int s = src[e];
    int t = dst[e];
    int pos = offs[s] + rank[e];
    const float4 ps4 = *(const float4*)(ps + (size_t)s * H);
    const float4 pd4 = *(const float4*)(pd + (size_t)t * H);
    float s0 = ps4.x + pd4.x; s0 = s0 > 0.f ? s0 : 0.2f * s0;
    float s1 = ps4.y + pd4.y; s1 = s1 > 0.f ? s1 : 0.2f * s1;
    float s2 = ps4.z + pd4.z; s2 = s2 > 0.f ? s2 : 0.2f * s2;
    float s3 = ps4.w + pd4.w; s3 = s3 > 0.f ? s3 : 0.2f * s3;
    union { __half2 h[2]; uint2 u; } pk;
    pk.h[0] = __floats2half2_rn(__expf(-s0), __expf(-s1));
    pk.h[1] = __floats2half2_rn(__expf(-s2), __expf(-s3));
    ec[pos] = make_uint4((unsigned)t, pk.u.x, pk.u.y, 0u);
}

// ---------------------------------------------------------------------------
// Kernel 5: per-node gather + fused normalize, 8-deep pipelined (MLP=8).
// One wave per node; lane covers cols {2*lane, 2*lane+1}.
// Edge stream read nontemporal (read-once); out stored nontemporal
// (write-once) so neither evicts x from L2/L3.
// NOTE: macro slot j also offsets k by j -> only valid in the 8-wide body;
// tail loop is hand-written (round-7 lesson).
// ---------------------------------------------------------------------------
union HU { __half2 h; unsigned u; };

#define GDECL(j) uvec4 q##j; float2 v##j;
#define GLOAD(j) q##j = __builtin_nontemporal_load((const uvec4*)ec + k + j);
#define GXLOAD(j) v##j = *(const float2*)(x + (size_t)q##j.x * D + lane2);
#define GACC(j) { HU u01, u23; u01.u = q##j.y; u23.u = q##j.z;              \
    float e0 = __low2float(u01.h),  e1 = __high2float(u01.h);               \
    float e2 = __low2float(u23.h),  e3 = __high2float(u23.h);               \
    a0x += e0 * v##j.x; a0y += e0 * v##j.y; rs0 += e0;                      \
    a1x += e1 * v##j.x; a1y += e1 * v##j.y; rs1 += e1;                      \
    a2x += e2 * v##j.x; a2y += e2 * v##j.y; rs2 += e2;                      \
    a3x += e3 * v##j.x; a3y += e3 * v##j.y; rs3 += e3; }

__global__ void gather_kernel(const float* __restrict__ x,
                              const float* __restrict__ w,
                              const int* __restrict__ offs,
                              const uint4* __restrict__ ec,
                              float* __restrict__ out,
                              int N) {
    int node = (int)(((long long)blockIdx.x * blockDim.x + threadIdx.x) >> 6);
    int lane = threadIdx.x & 63;
    if (node >= N) return;
    int lane2 = lane * 2;
    float a0x = 0, a0y = 0, a1x = 0, a1y = 0, a2x = 0, a2y = 0, a3x = 0, a3y = 0;
    float rs0 = 0, rs1 = 0, rs2 = 0, rs3 = 0;
    int beg = offs[node], end = offs[node + 1];
    int k = beg;
    for (; k + 8 <= end; k += 8) {
        GDECL(0) GDECL(1) GDECL(2) GDECL(3) GDECL(4) GDECL(5) GDECL(6) GDECL(7)
        GLOAD(0) GLOAD(1) GLOAD(2) GLOAD(3) GLOAD(4) GLOAD(5) GLOAD(6) GLOAD(7)
        GXLOAD(0) GXLOAD(1) GXLOAD(2) GXLOAD(3) GXLOAD(4) GXLOAD(5) GXLOAD(6) GXLOAD(7)
        GACC(0) GACC(1) GACC(2) GACC(3) GACC(4) GACC(5) GACC(6) GACC(7)
    }
    for (; k < end; ++k) {                 // hand-written tail: index k ONLY
        uvec4 q = __builtin_nontemporal_load((const uvec4*)ec + k);
        float2 v = *(const float2*)(x + (size_t)q.x * D + lane2);
        HU u01, u23; u01.u = q.y; u23.u = q.z;
        float e0 = __low2float(u01.h),  e1 = __high2float(u01.h);
        float e2 = __low2float(u23.h),  e3 = __high2float(u23.h);
        a0x += e0 * v.x; a0y += e0 * v.y; rs0 += e0;
        a1x += e1 * v.x; a1y += e1 * v.y; rs1 += e1;
        a2x += e2 * v.x; a2y += e2 * v.y; rs2 += e2;
        a3x += e3 * v.x; a3y += e3 * v.y; rs3 += e3;
    }
    float i0 = 1.0f / rs0, i1 = 1.0f / rs1, i2 = 1.0f / rs2, i3 = 1.0f / rs3;
    size_t nd = (size_t)N * D;
    size_t b = (size_t)node * D + lane2;
    const float2 w0 = *(const float2*)(w + 0 * D + lane2);
    const float2 w1 = *(const float2*)(w + 1 * D + lane2);
    const float2 w2 = *(const float2*)(w + 2 * D + lane2);
    const float2 w3 = *(const float2*)(w + 3 * D + lane2);
    fvec2 o0 = {a0x * w0.x * i0, a0y * w0.y * i0};
    fvec2 o1 = {a1x * w1.x * i1, a1y * w1.y * i1};
    fvec2 o2 = {a2x * w2.x * i2, a2y * w2.y * i2};
    fvec2 o3 = {a3x * w3.x * i3, a3y * w3.y * i3};
    __builtin_nontemporal_store(o0, (fvec2*)(out + 0 * nd + b));
    __builtin_nontemporal_store(o1, (fvec2*)(out + 1 * nd + b));
    __builtin_nontemporal_store(o2, (fvec2*)(out + 2 * nd + b));
    __builtin_nontemporal_store(o3, (fvec2*)(out + 3 * nd + b));
}

extern "C" void kernel_launch(void* const* d_in, const int* in_sizes, int n_in,
                              void* d_out, int out_size, void* d_ws, size_t ws_size,
                              hipStream_t stream) {
    const float* x    = (const float*)d_in[0];
    const float* w    = (const float*)d_in[1];
    const float* attn = (const float*)d_in[2];
    const int*   edge = (const int*)d_in[3];

    int N = in_sizes[0] / D;
    int E = in_sizes[3] / 2;
    const int* src = edge;
    const int* dst = edge + E;
    float* out = (float*)d_out;

    int nb = (N + 1023) / 1024;

    // workspace layout (ec first for 16B alignment); total ~36.0 MB
    char* wsp = (char*)d_ws;
    uint4* ec = (uint4*)wsp;       wsp += (size_t)E * sizeof(uint4);
    float* ps     = (float*)wsp;   wsp += (size_t)N * H * sizeof(float);
    float* pd     = (float*)wsp;   wsp += (size_t)N * H * sizeof(float);
    int*   counts = (int*)wsp;     wsp += (size_t)N * sizeof(int);
    int*   rank   = (int*)wsp;     wsp += (size_t)E * sizeof(int);
    int*   offs   = (int*)wsp;     wsp += ((size_t)N + 1) * sizeof(int);
    int*   bsum   = (int*)wsp;     wsp += (size_t)nb * sizeof(int);
    int*   boff   = (int*)wsp;     wsp += (size_t)nb * sizeof(int);

    hipMemsetAsync(counts, 0, (size_t)N * sizeof(int), stream);

    int nbP = (N + 3) / 4;           // proj blocks (4 nodes per 256-thr block)
    int nbC = (E + 255) / 256;       // count blocks
    proj_count_kernel<<<nbP + nbC, 256, 0, stream>>>(x, w, attn, ps, pd, src,
                                                     counts, rank, N, E, nbP);
    scan1_kernel<<<nb, 1024, 0, stream>>>(counts, offs, bsum, N);
    scan2_kernel<<<1, 64, 0, stream>>>(bsum, boff, nb);
    scan3_kernel<<<(N + 255) / 256, 256, 0, stream>>>(offs, boff, N, E);
    scatter_kernel<<<(E + 255) / 256, 256, 0, stream>>>(src, dst, rank, offs, ps, pd, ec, E);
    gather_kernel<<<(N + 3) / 4, 256, 0, stream>>>(x, w, offs, ec, out, N);
}

// Round 10
// 335.313 us; speedup vs baseline: 1.4683x; 1.0565x over previous
//
#include <hip/hip_runtime.h>
#include <hip/hip_fp16.h>

#define D 128
#define H 4

typedef unsigned int uvec4 __attribute__((ext_vector_type(4)));

// ---------------------------------------------------------------------------
// Kernel 1 (fused): blocks [0,nbP) compute per-node projections ps/pd;
// blocks [nbP, nbP+nbC) histogram src AND record each edge's rank
// (rank[e] = old count) so the CSR scatter needs no second atomic.
// ---------------------------------------------------------------------------
__global__ void proj_count_kernel(const float* __restrict__ x,
                                  const float* __restrict__ w,
                                  const float* __restrict__ attn,
                                  float* __restrict__ ps,
                                  float* __restrict__ pd,
                                  const int* __restrict__ src,
                                  int* __restrict__ counts,
                                  int* __restrict__ rank,
                                  int N, int E, int nbP) {
    int bid = blockIdx.x;
    if (bid < nbP) {
        int node = (int)(((long long)bid * blockDim.x + threadIdx.x) >> 6);
        int lane = threadIdx.x & 63;
        if (node >= N) return;
        float x0 = x[(size_t)node * D + lane];
        float x1 = x[(size_t)node * D + 64 + lane];
#pragma unroll
        for (int h = 0; h < H; ++h) {
            float hv0 = x0 * w[h * D + lane];
            float hv1 = x1 * w[h * D + 64 + lane];
            float psv = hv0 * attn[h * 2 * D + lane]     + hv1 * attn[h * 2 * D + 64 + lane];
            float pdv = hv0 * attn[h * 2 * D + D + lane] + hv1 * attn[h * 2 * D + D + 64 + lane];
#pragma unroll
            for (int off = 32; off > 0; off >>= 1) {
                psv += __shfl_xor(psv, off);
                pdv += __shfl_xor(pdv, off);
            }
            if (lane == 0) {
                ps[(size_t)node * H + h] = psv;
                pd[(size_t)node * H + h] = pdv;
            }
        }
    } else {
        int e = (bid - nbP) * blockDim.x + threadIdx.x;
        if (e < E) rank[e] = atomicAdd(counts + src[e], 1);
    }
}

// ---------------------------------------------------------------------------
// Scan pass 1: block-local exclusive scan of counts; block total to bsum.
// ---------------------------------------------------------------------------
__global__ void scan1_kernel(const int* __restrict__ counts,
                             int* __restrict__ offs,
                             int* __restrict__ bsum, int N) {
    __shared__ int wsum[16];
    __shared__ int woffi[16];
    int tid = threadIdx.x, lane = tid & 63, wid = tid >> 6;
    int i = blockIdx.x * 1024 + tid;
    int v = (i < N) ? counts[i] : 0;
    int acc = v;
#pragma unroll
    for (int d = 1; d < 64; d <<= 1) {
        int t = __shfl_up(acc, d);
        if (lane >= d) acc += t;
    }
    if (lane == 63) wsum[wid] = acc;
    __syncthreads();
    if (wid == 0) {
        int wv = (lane < 16) ? wsum[lane] : 0;
        int wacc = wv;
#pragma unroll
        for (int d = 1; d < 16; d <<= 1) {
            int t = __shfl_up(wacc, d);
            if (lane >= d) wacc += t;
        }
        if (lane < 16) woffi[lane] = wacc;
    }
    __syncthreads();
    int bexcl = (wid == 0) ? 0 : woffi[wid - 1];
    if (i < N) offs[i] = bexcl + (acc - v);
    if (tid == 0) bsum[blockIdx.x] = woffi[15];
}

// ---------------------------------------------------------------------------
// Scan pass 2: one wave scans block sums (supports nb <= 512).
// ---------------------------------------------------------------------------
__global__ void scan2_kernel(const int* __restrict__ bsum, int* __restrict__ boff, int nb) {
    int lane = threadIdx.x;
    int k = (nb + 63) >> 6;
    int local[8];
    int s = 0;
#pragma unroll 8
    for (int j = 0; j < k; ++j) {
        int idx = lane * k + j;
        local[j] = (idx < nb) ? bsum[idx] : 0;
        s += local[j];
    }
    int acc = s;
#pragma unroll
    for (int d = 1; d < 64; d <<= 1) {
        int t = __shfl_up(acc, d);
        if (lane >= d) acc += t;
    }
    int excl = acc - s;
#pragma unroll 8
    for (int j = 0; j < k; ++j) {
        int idx = lane * k + j;
        if (idx < nb) boff[idx] = excl;
        excl += local[j];
    }
}

// ---------------------------------------------------------------------------
// Scan pass 3: add block offsets; offs[N] = E.
// ---------------------------------------------------------------------------
__global__ void scan3_kernel(int* __restrict__ offs, const int* __restrict__ boff,
                             int N, int E) {
    int i = blockIdx.x * blockDim.x + threadIdx.x;
    if (i < N) offs[i] += boff[i >> 10];
    if (i == 0) offs[N] = E;
}

// ---------------------------------------------------------------------------
// Kernel 4: CSR scatter, atomic-free (pos = offs[src] + rank[e]).
// Packs {dst, e01_fp16, e23_fp16} into ONE 16-byte record -> one random
// cache-line RMW per edge.
// ---------------------------------------------------------------------------
__global__ void scatter_kernel(const int* __restrict__ src, const int* __restrict__ dst,
                               const int* __restrict__ rank, const int* __restrict__ offs,
                               const float* __restrict__ ps, const float* __restrict__ pd,
                               uint4* __restrict__ ec, int E) {
    int e = blockIdx.x * blockDim.x + threadIdx.x;
    if (e >= E) return;
    int s = src[e];
    int t = dst[e];
    int pos = offs[s] + rank[e];
    const float4 ps4 = *(const float4*)(ps + (size_t)s * H);
    const float4 pd4 = *(const float4*)(pd + (size_t)t * H);
    float s0 = ps4.x + pd4.x; s0 = s0 > 0.f ? s0 : 0.2f * s0;
    float s1 = ps4.y + pd4.y; s1 = s1 > 0.f ? s1 : 0.2f * s1;
    float s2 = ps4.z + pd4.z; s2 = s2 > 0.f ? s2 : 0.2f * s2;
    float s3 = ps4.w + pd4.w; s3 = s3 > 0.f ? s3 : 0.2f * s3;
    union { __half2 h[2]; uint2 u; } pk;
    pk.h[0] = __floats2half2_rn(__expf(-s0), __expf(-s1));
    pk.h[1] = __floats2half2_rn(__expf(-s2), __expf(-s3));
    ec[pos] = make_uint4((unsigned)t, pk.u.x, pk.u.y, 0u);
}

// ---------------------------------------------------------------------------
// Kernel 5: per-node gather + fused normalize, 8-deep pipelined (MLP=8).
// One wave per node; lane covers cols {2*lane, 2*lane+1}. Plain cached
// loads/stores (round-9 nontemporal hints REGRESSED: ec stream lost L2
// residency -> +35us; reverted).
// NOTE: macro slot j also offsets k by j -> only valid in the 8-wide body;
// tail loop is hand-written (round-7 lesson).
// ---------------------------------------------------------------------------
union HU { __half2 h; unsigned u; };

#define GDECL(j) uvec4 q##j; float2 v##j;
#define GLOAD(j) q##j = *((const uvec4*)ec + k + j);
#define GXLOAD(j) v##j = *(const float2*)(x + (size_t)q##j.x * D + lane2);
#define GACC(j) { HU u01, u23; u01.u = q##j.y; u23.u = q##j.z;              \
    float e0 = __low2float(u01.h),  e1 = __high2float(u01.h);               \
    float e2 = __low2float(u23.h),  e3 = __high2float(u23.h);               \
    a0x += e0 * v##j.x; a0y += e0 * v##j.y; rs0 += e0;                      \
    a1x += e1 * v##j.x; a1y += e1 * v##j.y; rs1 += e1;                      \
    a2x += e2 * v##j.x; a2y += e2 * v##j.y; rs2 += e2;                      \
    a3x += e3 * v##j.x; a3y += e3 * v##j.y; rs3 += e3; }

__global__ void gather_kernel(const float* __restrict__ x,
                              const float* __restrict__ w,
                              const int* __restrict__ offs,
                              const uint4* __restrict__ ec,
                              float* __restrict__ out,
                              int N, int nodeBeg, int nodeEnd) {
    int node = nodeBeg + (int)(((long long)blockIdx.x * blockDim.x + threadIdx.x) >> 6);
    int lane = threadIdx.x & 63;
    if (node >= nodeEnd) return;
    int lane2 = lane * 2;
    float a0x = 0, a0y = 0, a1x = 0, a1y = 0, a2x = 0, a2y = 0, a3x = 0, a3y = 0;
    float rs0 = 0, rs1 = 0, rs2 = 0, rs3 = 0;
    int beg = offs[node], end = offs[node + 1];
    int k = beg;
    for (; k + 8 <= end; k += 8) {
        GDECL(0) GDECL(1) GDECL(2) GDECL(3) GDECL(4) GDECL(5) GDECL(6) GDECL(7)
        GLOAD(0) GLOAD(1) GLOAD(2) GLOAD(3) GLOAD(4) GLOAD(5) GLOAD(6) GLOAD(7)
        GXLOAD(0) GXLOAD(1) GXLOAD(2) GXLOAD(3) GXLOAD(4) GXLOAD(5) GXLOAD(6) GXLOAD(7)
        GACC(0) GACC(1) GACC(2) GACC(3) GACC(4) GACC(5) GACC(6) GACC(7)
    }
    for (; k < end; ++k) {                 // hand-written tail: index k ONLY
        uvec4 q = *((const uvec4*)ec + k);
        float2 v = *(const float2*)(x + (size_t)q.x * D + lane2);
        HU u01, u23; u01.u = q.y; u23.u = q.z;
        float e0 = __low2float(u01.h),  e1 = __high2float(u01.h);
        float e2 = __low2float(u23.h),  e3 = __high2float(u23.h);
        a0x += e0 * v.x; a0y += e0 * v.y; rs0 += e0;
        a1x += e1 * v.x; a1y += e1 * v.y; rs1 += e1;
        a2x += e2 * v.x; a2y += e2 * v.y; rs2 += e2;
        a3x += e3 * v.x; a3y += e3 * v.y; rs3 += e3;
    }
    float i0 = 1.0f / rs0, i1 = 1.0f / rs1, i2 = 1.0f / rs2, i3 = 1.0f / rs3;
    size_t nd = (size_t)N * D;
    size_t b = (size_t)node * D + lane2;
    const float2 w0 = *(const float2*)(w + 0 * D + lane2);
    const float2 w1 = *(const float2*)(w + 1 * D + lane2);
    const float2 w2 = *(const float2*)(w + 2 * D + lane2);
    const float2 w3 = *(const float2*)(w + 3 * D + lane2);
    *(float2*)(out + 0 * nd + b) = make_float2(a0x * w0.x * i0, a0y * w0.y * i0);
    *(float2*)(out + 1 * nd + b) = make_float2(a1x * w1.x * i1, a1y * w1.y * i1);
    *(float2*)(out + 2 * nd + b) = make_float2(a2x * w2.x * i2, a2y * w2.y * i2);
    *(float2*)(out + 3 * nd + b) = make_float2(a3x * w3.x * i3, a3y * w3.y * i3);
}

extern "C" void kernel_launch(void* const* d_in, const int* in_sizes, int n_in,
                              void* d_out, int out_size, void* d_ws, size_t ws_size,
                              hipStream_t stream) {
    const float* x    = (const float*)d_in[0];
    const float* w    = (const float*)d_in[1];
    const float* attn = (const float*)d_in[2];
    const int*   edge = (const int*)d_in[3];

    int N = in_sizes[0] / D;
    int E = in_sizes[3] / 2;
    const int* src = edge;
    const int* dst = edge + E;
    float* out = (float*)d_out;

    int nb = (N + 1023) / 1024;

    // workspace layout (ec first for 16B alignment); total ~36.0 MB
    char* wsp = (char*)d_ws;
    uint4* ec = (uint4*)wsp;       wsp += (size_t)E * sizeof(uint4);
    float* ps     = (float*)wsp;   wsp += (size_t)N * H * sizeof(float);
    float* pd     = (float*)wsp;   wsp += (size_t)N * H * sizeof(float);
    int*   counts = (int*)wsp;     wsp += (size_t)N * sizeof(int);
    int*   rank   = (int*)wsp;     wsp += (size_t)E * sizeof(int);
    int*   offs   = (int*)wsp;     wsp += ((size_t)N + 1) * sizeof(int);
    int*   bsum   = (int*)wsp;     wsp += (size_t)nb * sizeof(int);
    int*   boff   = (int*)wsp;     wsp += (size_t)nb * sizeof(int);

    hipMemsetAsync(counts, 0, (size_t)N * sizeof(int), stream);

    int nbP = (N + 3) / 4;           // proj blocks (4 nodes per 256-thr block)
    int nbC = (E + 255) / 256;       // count blocks
    proj_count_kernel<<<nbP + nbC, 256, 0, stream>>>(x, w, attn, ps, pd, src,
                                                     counts, rank, N, E, nbP);
    scan1_kernel<<<nb, 1024, 0, stream>>>(counts, offs, bsum, N);
    scan2_kernel<<<1, 64, 0, stream>>>(bsum, boff, nb);
    scan3_kernel<<<(N + 255) / 256, 256, 0, stream>>>(offs, boff, N, E);
    scatter_kernel<<<(E + 255) / 256, 256, 0, stream>>>(src, dst, rank, offs, ps, pd, ec, E);
    // gather split into two half-range dispatches: same work, and lets any
    // hidden >80us prep kernel surface in the top-5 profile.
    int half = N / 2;
    gather_kernel<<<(half + 3) / 4, 256, 0, stream>>>(x, w, offs, ec, out, N, 0, half);
    gather_kernel<<<((N - half) + 3) / 4, 256, 0, stream>>>(x, w, offs, ec, out, N, half, N);
}

// Round 11
// 318.767 us; speedup vs baseline: 1.5445x; 1.0519x over previous
//
#include <hip/hip_runtime.h>
#include <hip/hip_fp16.h>

#define D 128
#define H 4
#define R 8   // histogram replicas (contention reduction)

typedef unsigned int uvec4 __attribute__((ext_vector_type(4)));

// ---------------------------------------------------------------------------
// Kernel 1 (fused): blocks [0,nbC) histogram src into REPLICATED counters
// counts[r][N] with r = edge-block & 7, recording each edge's within-replica
// rank (ushort). Blocks [nbC, nbC+nbP) compute per-node projections ps/pd and
// (optionally) the fp16 copy of x used by gather. Count blocks go FIRST so
// the atomic long-pole starts at t=0.
// ---------------------------------------------------------------------------
__global__ void proj_count_kernel(const float* __restrict__ x,
                                  const float* __restrict__ w,
                                  const float* __restrict__ attn,
                                  float* __restrict__ ps,
                                  float* __restrict__ pd,
                                  __half* __restrict__ xh,   // may be null
                                  const int* __restrict__ src,
                                  int* __restrict__ counts,
                                  unsigned short* __restrict__ rank,
                                  int N, int E, int nbC) {
    int bid = blockIdx.x;
    if (bid < nbC) {
        int e = bid * 256 + threadIdx.x;
        if (e < E) {
            int s = src[e];
            int r = bid & (R - 1);               // == (e>>8)&7, wave-uniform
            rank[e] = (unsigned short)atomicAdd(counts + (size_t)r * N + s, 1);
        }
    } else {
        int node = (int)(((long long)(bid - nbC) * blockDim.x + threadIdx.x) >> 6);
        int lane = threadIdx.x & 63;
        if (node >= N) return;
        float x0 = x[(size_t)node * D + lane];
        float x1 = x[(size_t)node * D + 64 + lane];
        if (xh) {
            xh[(size_t)node * D + lane]      = __float2half(x0);
            xh[(size_t)node * D + 64 + lane] = __float2half(x1);
        }
#pragma unroll
        for (int h = 0; h < H; ++h) {
            float hv0 = x0 * w[h * D + lane];
            float hv1 = x1 * w[h * D + 64 + lane];
            float psv = hv0 * attn[h * 2 * D + lane]     + hv1 * attn[h * 2 * D + 64 + lane];
            float pdv = hv0 * attn[h * 2 * D + D + lane] + hv1 * attn[h * 2 * D + D + 64 + lane];
#pragma unroll
            for (int off = 32; off > 0; off >>= 1) {
                psv += __shfl_xor(psv, off);
                pdv += __shfl_xor(pdv, off);
            }
            if (lane == 0) {
                ps[(size_t)node * H + h] = psv;
                pd[(size_t)node * H + h] = pdv;
            }
        }
    }
}

// ---------------------------------------------------------------------------
// Scan pass 1: per node, reduce the R replica counts (writing back each
// replica's EXCLUSIVE base within the node), then block-local exclusive scan
// of node totals; block total to bsum.
// ---------------------------------------------------------------------------
__global__ void scan1_kernel(int* __restrict__ counts,
                             int* __restrict__ offs,
                             int* __restrict__ bsum, int N) {
    __shared__ int wsum[16];
    __shared__ int woffi[16];
    int tid = threadIdx.x, lane = tid & 63, wid = tid >> 6;
    int i = blockIdx.x * 1024 + tid;
    int v = 0;
    if (i < N) {
        int c[R];
#pragma unroll
        for (int r = 0; r < R; ++r) { c[r] = counts[(size_t)r * N + i]; v += c[r]; }
        int b = 0;
#pragma unroll
        for (int r = 0; r < R; ++r) { int t = c[r]; counts[(size_t)r * N + i] = b; b += t; }
    }
    int acc = v;
#pragma unroll
    for (int d = 1; d < 64; d <<= 1) {
        int t = __shfl_up(acc, d);
        if (lane >= d) acc += t;
    }
    if (lane == 63) wsum[wid] = acc;
    __syncthreads();
    if (wid == 0) {
        int wv = (lane < 16) ? wsum[lane] : 0;
        int wacc = wv;
#pragma unroll
        for (int d = 1; d < 16; d <<= 1) {
            int t = __shfl_up(wacc, d);
            if (lane >= d) wacc += t;
        }
        if (lane < 16) woffi[lane] = wacc;
    }
    __syncthreads();
    int bexcl = (wid == 0) ? 0 : woffi[wid - 1];
    if (i < N) offs[i] = bexcl + (acc - v);
    if (tid == 0) bsum[blockIdx.x] = woffi[15];
}

// ---------------------------------------------------------------------------
// Scan pass 2: one wave scans block sums (supports nb <= 512).
// ---------------------------------------------------------------------------
__global__ void scan2_kernel(const int* __restrict__ bsum, int* __restrict__ boff, int nb) {
    int lane = threadIdx.x;
    int k = (nb + 63) >> 6;
    int local[8];
    int s = 0;
#pragma unroll 8
    for (int j = 0; j < k; ++j) {
        int idx = lane * k + j;
        local[j] = (idx < nb) ? bsum[idx] : 0;
        s += local[j];
    }
    int acc = s;
#pragma unroll
    for (int d = 1; d < 64; d <<= 1) {
        int t = __shfl_up(acc, d);
        if (lane >= d) acc += t;
    }
    int excl = acc - s;
#pragma unroll 8
    for (int j = 0; j < k; ++j) {
        int idx = lane * k + j;
        if (idx < nb) boff[idx] = excl;
        excl += local[j];
    }
}

// ---------------------------------------------------------------------------
// Scan pass 3: add block offsets; offs[N] = E.
// ---------------------------------------------------------------------------
__global__ void scan3_kernel(int* __restrict__ offs, const int* __restrict__ boff,
                             int N, int E) {
    int i = blockIdx.x * blockDim.x + threadIdx.x;
    if (i < N) offs[i] += boff[i >> 10];
    if (i == 0) offs[N] = E;
}

// ---------------------------------------------------------------------------
// Kernel 4: CSR scatter, atomic-free:
//   pos = offs[src] + replicaBase(counts[r][src]) + rank[e]
// Packs {dst, e01_fp16, e23_fp16} into ONE 16-byte record.
// ---------------------------------------------------------------------------
__global__ void scatter_kernel(const int* __restrict__ src, const int* __restrict__ dst,
                               const unsigned short* __restrict__ rank,
                               const int* __restrict__ offs,
                               const int* __restrict__ counts,
                               const float* __restrict__ ps, const float* __restrict__ pd,
                               uint4* __restrict__ ec, int N, int E) {
    int e = blockIdx.x * blockDim.x + threadIdx.x;
    if (e >= E) return;
    int s = src[e];
    int t = dst[e];
    int r = (e >> 8) & (R - 1);
    int pos = offs[s] + counts[(size_t)r * N + s] + (int)rank[e];
    const float4 ps4 = *(const float4*)(ps + (size_t)s * H);
    const float4 pd4 = *(const float4*)(pd + (size_t)t * H);
    float s0 = ps4.x + pd4.x; s0 = s0 > 0.f ? s0 : 0.2f * s0;
    float s1 = ps4.y + pd4.y; s1 = s1 > 0.f ? s1 : 0.2f * s1;
    float s2 = ps4.z + pd4.z; s2 = s2 > 0.f ? s2 : 0.2f * s2;
    float s3 = ps4.w + pd4.w; s3 = s3 > 0.f ? s3 : 0.2f * s3;
    union { __half2 h[2]; uint2 u; } pk;
    pk.h[0] = __floats2half2_rn(__expf(-s0), __expf(-s1));
    pk.h[1] = __floats2half2_rn(__expf(-s2), __expf(-s3));
    ec[pos] = make_uint4((unsigned)t, pk.u.x, pk.u.y, 0u);
}

// ---------------------------------------------------------------------------
// Kernel 5: per-node gather + fused normalize, 8-deep pipelined (MLP=8).
// XH=1: x rows read as fp16 (half request bytes). Plain cached loads/stores
// (round-9 NT hints regressed). Tail loop hand-written (round-7 lesson).
// ---------------------------------------------------------------------------
union HU { __half2 h; unsigned u; };

#define GDECL(j) uvec4 q##j; float2 v##j;
#define GLOAD(j) q##j = *((const uvec4*)ec + k + j);
#define GXLOADF(j) v##j = *(const float2*)(x + (size_t)q##j.x * D + lane2);
#define GXLOADH(j) { __half2 hv = *(const __half2*)(xh + (size_t)q##j.x * D + lane2); \
                     v##j = __half22float2(hv); }
#define GACC(j) { HU u01, u23; u01.u = q##j.y; u23.u = q##j.z;              \
    float e0 = __low2float(u01.h),  e1 = __high2float(u01.h);               \
    float e2 = __low2float(u23.h),  e3 = __high2float(u23.h);               \
    a0x += e0 * v##j.x; a0y += e0 * v##j.y; rs0 += e0;                      \
    a1x += e1 * v##j.x; a1y += e1 * v##j.y; rs1 += e1;                      \
    a2x += e2 * v##j.x; a2y += e2 * v##j.y; rs2 += e2;                      \
    a3x += e3 * v##j.x; a3y += e3 * v##j.y; rs3 += e3; }

template <int XH>
__global__ void gather_kernel(const float* __restrict__ x,
                              const __half* __restrict__ xh,
                              const float* __restrict__ w,
                              const int* __restrict__ offs,
                              const uint4* __restrict__ ec,
                              float* __restrict__ out,
                              int N, int nodeBeg, int nodeEnd) {
    int node = nodeBeg + (int)(((long long)blockIdx.x * blockDim.x + threadIdx.x) >> 6);
    int lane = threadIdx.x & 63;
    if (node >= nodeEnd) return;
    int lane2 = lane * 2;
    float a0x = 0, a0y = 0, a1x = 0, a1y = 0, a2x = 0, a2y = 0, a3x = 0, a3y = 0;
    float rs0 = 0, rs1 = 0, rs2 = 0, rs3 = 0;
    int beg = offs[node], end = offs[node + 1];
    int k = beg;
    for (; k + 8 <= end; k += 8) {
        GDECL(0) GDECL(1) GDECL(2) GDECL(3) GDECL(4) GDECL(5) GDECL(6) GDECL(7)
        GLOAD(0) GLOAD(1) GLOAD(2) GLOAD(3) GLOAD(4) GLOAD(5) GLOAD(6) GLOAD(7)
        if (XH) { GXLOADH(0) GXLOADH(1) GXLOADH(2) GXLOADH(3) GXLOADH(4) GXLOADH(5) GXLOADH(6) GXLOADH(7) }
        else    { GXLOADF(0) GXLOADF(1) GXLOADF(2) GXLOADF(3) GXLOADF(4) GXLOADF(5) GXLOADF(6) GXLOADF(7) }
        GACC(0) GACC(1) GACC(2) GACC(3) GACC(4) GACC(5) GACC(6) GACC(7)
    }
    for (; k < end; ++k) {                 // hand-written tail: index k ONLY
        uvec4 q = *((const uvec4*)ec + k);
        float2 v;
        if (XH) { __half2 hv = *(const __half2*)(xh + (size_t)q.x * D + lane2); v = __half22float2(hv); }
        else    { v = *(const float2*)(x + (size_t)q.x * D + lane2); }
        HU u01, u23; u01.u = q.y; u23.u = q.z;
        float e0 = __low2float(u01.h),  e1 = __high2float(u01.h);
        float e2 = __low2float(u23.h),  e3 = __high2float(u23.h);
        a0x += e0 * v.x; a0y += e0 * v.y; rs0 += e0;
        a1x += e1 * v.x; a1y += e1 * v.y; rs1 += e1;
        a2x += e2 * v.x; a2y += e2 * v.y; rs2 += e2;
        a3x += e3 * v.x; a3y += e3 * v.y; rs3 += e3;
    }
    float i0 = 1.0f / rs0, i1 = 1.0f / rs1, i2 = 1.0f / rs2, i3 = 1.0f / rs3;
    size_t nd = (size_t)N * D;
    size_t b = (size_t)node * D + lane2;
    const float2 w0 = *(const float2*)(w + 0 * D + lane2);
    const float2 w1 = *(const float2*)(w + 1 * D + lane2);
    const float2 w2 = *(const float2*)(w + 2 * D + lane2);
    const float2 w3 = *(const float2*)(w + 3 * D + lane2);
    *(float2*)(out + 0 * nd + b) = make_float2(a0x * w0.x * i0, a0y * w0.y * i0);
    *(float2*)(out + 1 * nd + b) = make_float2(a1x * w1.x * i1, a1y * w1.y * i1);
    *(float2*)(out + 2 * nd + b) = make_float2(a2x * w2.x * i2, a2y * w2.y * i2);
    *(float2*)(out + 3 * nd + b) = make_float2(a3x * w3.x * i3, a3y * w3.y * i3);
}

extern "C" void kernel_launch(void* const* d_in, const int* in_sizes, int n_in,
                              void* d_out, int out_size, void* d_ws, size_t ws_size,
                              hipStream_t stream) {
    const float* x    = (const float*)d_in[0];
    const float* w    = (const float*)d_in[1];
    const float* attn = (const float*)d_in[2];
    const int*   edge = (const int*)d_in[3];

    int N = in_sizes[0] / D;
    int E = in_sizes[3] / 2;
    const int* src = edge;
    const int* dst = edge + E;
    float* out = (float*)d_out;

    int nb = (N + 1023) / 1024;

    // Sizes
    size_t sz_ec     = (size_t)E * 16;
    size_t sz_xh     = (size_t)N * D * 2;
    size_t sz_psd    = (size_t)N * H * 4;       // each of ps, pd
    size_t sz_counts = (size_t)R * N * 4;
    size_t sz_offs   = ((size_t)N + 1) * 4;
    size_t sz_nb     = (size_t)nb * 4;
    size_t base_need = sz_ec + 2 * sz_psd + sz_counts + sz_offs + 2 * sz_nb
                     + (size_t)E * 2;           // rank (ushort)
    bool use_xh = ws_size >= base_need + sz_xh + 1024;

    char* wsp = (char*)d_ws;
    uint4* ec = (uint4*)wsp;            wsp += sz_ec;
    __half* xh = nullptr;
    if (use_xh) { xh = (__half*)wsp;    wsp += sz_xh; }
    float* ps     = (float*)wsp;        wsp += sz_psd;
    float* pd     = (float*)wsp;        wsp += sz_psd;
    int*   counts = (int*)wsp;          wsp += sz_counts;
    int*   offs   = (int*)wsp;          wsp += sz_offs;
    int*   bsum   = (int*)wsp;          wsp += sz_nb;
    int*   boff   = (int*)wsp;          wsp += sz_nb;
    unsigned short* rank = (unsigned short*)wsp;

    hipMemsetAsync(counts, 0, sz_counts, stream);

    int nbC = (E + 255) / 256;       // count blocks (run first)
    int nbP = (N + 3) / 4;           // proj blocks
    proj_count_kernel<<<nbC + nbP, 256, 0, stream>>>(x, w, attn, ps, pd, xh, src,
                                                     counts, rank, N, E, nbC);
    scan1_kernel<<<nb, 1024, 0, stream>>>(counts, offs, bsum, N);
    scan2_kernel<<<1, 64, 0, stream>>>(bsum, boff, nb);
    scan3_kernel<<<(N + 255) / 256, 256, 0, stream>>>(offs, boff, N, E);
    scatter_kernel<<<(E + 255) / 256, 256, 0, stream>>>(src, dst, rank, offs, counts,
                                                        ps, pd, ec, N, E);
    int half = N / 2;
    if (use_xh) {
        gather_kernel<1><<<(half + 3) / 4, 256, 0, stream>>>(x, xh, w, offs, ec, out, N, 0, half);
        gather_kernel<1><<<((N - half) + 3) / 4, 256, 0, stream>>>(x, xh, w, offs, ec, out, N, half, N);
    } else {
        gather_kernel<0><<<(half + 3) / 4, 256, 0, stream>>>(x, xh, w, offs, ec, out, N, 0, half);
        gather_kernel<0><<<((N - half) + 3) / 4, 256, 0, stream>>>(x, xh, w, offs, ec, out, N, half, N);
    }
}